// Round 9
// baseline (83.188 us; speedup 1.0000x reference)
//
#include <hip/hip_runtime.h>

// Mixture-of-64-tiny-experts, fp32, packed-pair (2 samples in v2f halves).
// R8: R4's proven builtin-pk structure (NO inline asm — R7's asm corrupted
// registers). Activations = Pade[5/4] tanh with:
//   (a) Pade constants loaded as duplicated pairs from the pack buffer
//       (runtime values -> ISel must keep <2 x float> ops packed; R6's
//       literal constants are what triggered full scalarization), and
//   (b) shared reciprocal: ONE rcp-pair serves all 4 layer-1 denominators
//       (prefix/suffix products), one more serves both layer-2 denominators.
// Trans per subnet: 26 (R4) -> 6 (2 rcp L1 + 2 rcp L2 + 2 exp2 gate).

#define NSUB 64
#define L2E  1.4426950408889634f   // log2(e)
#define CONST_OFF (NSUB * 96)      // constants block in pack buffer

typedef float v2f __attribute__((ext_vector_type(2)));

__device__ __forceinline__ v2f pk_fma(v2f a, v2f b, v2f c) {
    return __builtin_elementwise_fma(a, b, c);
}
__device__ __forceinline__ v2f sp(float s) { return v2f{s, s}; }

// clamp both halves to [-1,1] (VOP3 med3, inline consts; per-half scalar ops
// proven non-disruptive to packing in R4)
__device__ __forceinline__ v2f med3_pair(v2f u) {
    v2f m;
    m.x = __builtin_amdgcn_fmed3f(u.x, -1.0f, 1.0f);
    m.y = __builtin_amdgcn_fmed3f(u.y, -1.0f, 1.0f);
    return m;
}

// exp2-based tanhshrink for the once-per-thread gating net (R4-proven code)
__device__ __forceinline__ v2f tanhshrink_exp(v2f a) {
    v2f s = a * 2.8853900817779268f;
    v2f e;
    e.x = __builtin_amdgcn_exp2f(s.x);
    e.y = __builtin_amdgcn_exp2f(s.y);
    v2f ep = e + 1.0f;
    v2f r;
    r.x = __builtin_amdgcn_rcpf(ep.x);
    r.y = __builtin_amdgcn_rcpf(ep.y);
    return pk_fma(sp(2.0f), r, a - 1.0f);
}

// Packed per-subnet params as DUPLICATED PAIRS, 96 floats (48 pair-slots):
// pair idx: [0:24) W1 (4x6) | [24:28) b1 | [28:36) W2 (2x4) | [36:38) b2
//           [38:44) Gw2*L2E | [44] Gb2*L2E | [45:48) pad
// Then at CONST_OFF: Pade constants as pairs {105,105,945,945,15,15,420,420}.
__global__ void pack_kernel(const float* __restrict__ W1, const float* __restrict__ b1,
                            const float* __restrict__ W2, const float* __restrict__ b2,
                            const float* __restrict__ Gw2, const float* __restrict__ Gb2,
                            float* __restrict__ ws)
{
    int s = threadIdx.x;
    if (s >= NSUB) return;
    float* f = ws + s * 96;
    for (int i = 0; i < 24; ++i) { float v = W1[s * 24 + i];       f[2*i] = v;      f[2*i+1] = v; }
    for (int i = 0; i < 4;  ++i) { float v = b1[s * 4 + i];        f[48+2*i] = v;   f[48+2*i+1] = v; }
    for (int i = 0; i < 8;  ++i) { float v = W2[s * 8 + i];        f[56+2*i] = v;   f[56+2*i+1] = v; }
    for (int i = 0; i < 2;  ++i) { float v = b2[s * 2 + i];        f[72+2*i] = v;   f[72+2*i+1] = v; }
    for (int i = 0; i < 6;  ++i) { float v = Gw2[s * 6 + i] * L2E; f[76+2*i] = v;   f[76+2*i+1] = v; }
    { float v = Gb2[s] * L2E; f[88] = v; f[89] = v; }
    f[90] = 0.f; f[91] = 0.f; f[92] = 0.f; f[93] = 0.f; f[94] = 0.f; f[95] = 0.f;
    if (s == 0) {
        float* c = ws + CONST_OFF;
        c[0] = 105.0f; c[1] = 105.0f;
        c[2] = 945.0f; c[3] = 945.0f;
        c[4] = 15.0f;  c[5] = 15.0f;
        c[6] = 420.0f; c[7] = 420.0f;
    }
}

__global__ __launch_bounds__(256) void moe_kernel(
    const float* __restrict__ x,
    const float* __restrict__ wpack,
    const float* __restrict__ Gw1, const float* __restrict__ Gb1,
    float* __restrict__ out)
{
    long t = blockIdx.x * blockDim.x + threadIdx.x;

    // Pade constants as opaque runtime pairs (forces packed codegen)
    const v2f* cc = (const v2f*)(wpack + CONST_OFF);
    const v2f C105 = cc[0], C945 = cc[1], C15 = cc[2], C420 = cc[3];

    const float4* xv = (const float4*)(x + t * 12);
    float4 a0 = xv[0];
    float4 a1 = xv[1];
    float4 a2 = xv[2];
    v2f xa[6] = { v2f{a0.x, a1.z}, v2f{a0.y, a1.w}, v2f{a0.z, a2.x},
                  v2f{a0.w, a2.y}, v2f{a1.x, a2.z}, v2f{a1.y, a2.w} };

    // ---- gating hidden: g = tanhshrink(Gw1 @ x + Gb1)  (once/thread) ----
    v2f ga[6];
#pragma unroll
    for (int j = 0; j < 6; ++j) {
        v2f s = sp(Gb1[j]);
#pragma unroll
        for (int i = 0; i < 6; ++i)
            s = pk_fma(sp(Gw1[j * 6 + i]), xa[i], s);
        ga[j] = tanhshrink_exp(s);
    }

    // ---- subnet loop, softmax folded into running num/denom ----
    v2f acc0 = sp(0.f), acc1 = sp(0.f), accE = sp(0.f);

#pragma unroll 2
    for (int sIdx = 0; sIdx < NSUB; ++sIdx) {
        const v2f* f2 = (const v2f*)(wpack + sIdx * 96);   // 48 duplicated pairs

        // layer-1 preactivations (bias as fma init)
        v2f s0 = pk_fma(f2[0],  xa[0], f2[24]);
        v2f s1 = pk_fma(f2[6],  xa[0], f2[25]);
        v2f s2 = pk_fma(f2[12], xa[0], f2[26]);
        v2f s3 = pk_fma(f2[18], xa[0], f2[27]);
#pragma unroll
        for (int i = 1; i < 6; ++i) {
            s0 = pk_fma(f2[i],      xa[i], s0);
            s1 = pk_fma(f2[6 + i],  xa[i], s1);
            s2 = pk_fma(f2[12 + i], xa[i], s2);
            s3 = pk_fma(f2[18 + i], xa[i], s3);
        }

        // Pade pieces: n = 945 + t(105+t), d = 945 + t(420+15t), xn = s*n
        v2f d0, d1, d2, d3, xn0, xn1, xn2, xn3;
        {
            v2f t0 = s0 * s0;
            xn0 = s0 * pk_fma(t0, t0 + C105, C945);
            d0  = pk_fma(t0, pk_fma(t0, C15, C420), C945);
            v2f t1 = s1 * s1;
            xn1 = s1 * pk_fma(t1, t1 + C105, C945);
            d1  = pk_fma(t1, pk_fma(t1, C15, C420), C945);
            v2f t2 = s2 * s2;
            xn2 = s2 * pk_fma(t2, t2 + C105, C945);
            d2  = pk_fma(t2, pk_fma(t2, C15, C420), C945);
            v2f t3 = s3 * s3;
            xn3 = s3 * pk_fma(t3, t3 + C105, C945);
            d3  = pk_fma(t3, pk_fma(t3, C15, C420), C945);
        }

        // shared reciprocal: R = 1/(d0 d1 d2 d3); r_i = (prod_{j!=i} d_j) * R
        v2f p01 = d0 * d1;
        v2f s23 = d2 * d3;
        v2f D   = p01 * s23;
        v2f R;
        R.x = __builtin_amdgcn_rcpf(D.x);
        R.y = __builtin_amdgcn_rcpf(D.y);
        v2f r0 = (d1 * s23) * R;
        v2f r1 = (d0 * s23) * R;
        v2f r2 = (p01 * d3) * R;
        v2f r3 = (p01 * d2) * R;

        // h = s - clamp(x*n/d)   (tanhshrink)
        v2f h0 = s0 - med3_pair(xn0 * r0);
        v2f h1 = s1 - med3_pair(xn1 * r1);
        v2f h2 = s2 - med3_pair(xn2 * r2);
        v2f h3 = s3 - med3_pair(xn3 * r3);

        // layer-2 preactivations
        v2f q0 = pk_fma(f2[28], h0, f2[36]);
        q0 = pk_fma(f2[29], h1, q0);
        q0 = pk_fma(f2[30], h2, q0);
        q0 = pk_fma(f2[31], h3, q0);
        v2f q1 = pk_fma(f2[32], h0, f2[37]);
        q1 = pk_fma(f2[33], h1, q1);
        q1 = pk_fma(f2[34], h2, q1);
        q1 = pk_fma(f2[35], h3, q1);

        // o = clamp(q*n/d) with shared rcp over the two denominators
        v2f tq0 = q0 * q0;
        v2f yn0 = q0 * pk_fma(tq0, tq0 + C105, C945);
        v2f e0  = pk_fma(tq0, pk_fma(tq0, C15, C420), C945);
        v2f tq1 = q1 * q1;
        v2f yn1 = q1 * pk_fma(tq1, tq1 + C105, C945);
        v2f e1  = pk_fma(tq1, pk_fma(tq1, C15, C420), C945);
        v2f P = e0 * e1;
        v2f Q;
        Q.x = __builtin_amdgcn_rcpf(P.x);
        Q.y = __builtin_amdgcn_rcpf(P.y);
        v2f o0 = med3_pair(yn0 * (e1 * Q));
        v2f o1 = med3_pair(yn1 * (e0 * Q));

        // gate logit (pre-scaled by log2e) -> exp2
        v2f la = pk_fma(f2[38], ga[0], f2[44]);
        la = pk_fma(f2[39], ga[1], la);
        la = pk_fma(f2[40], ga[2], la);
        la = pk_fma(f2[41], ga[3], la);
        la = pk_fma(f2[42], ga[4], la);
        la = pk_fma(f2[43], ga[5], la);
        v2f ea;
        ea.x = __builtin_amdgcn_exp2f(la.x);
        ea.y = __builtin_amdgcn_exp2f(la.y);

        accE = accE + ea;
        acc0 = pk_fma(ea, o0, acc0);
        acc1 = pk_fma(ea, o1, acc1);
    }

    v2f ra;
    ra.x = __builtin_amdgcn_rcpf(accE.x);
    ra.y = __builtin_amdgcn_rcpf(accE.y);
    acc0 = acc0 * ra;
    acc1 = acc1 * ra;

    float4 r;
    r.x = acc0.x; r.y = acc1.x; r.z = acc0.y; r.w = acc1.y;
    ((float4*)&out[t * 4])[0] = r;
}

extern "C" void kernel_launch(void* const* d_in, const int* in_sizes, int n_in,
                              void* d_out, int out_size, void* d_ws, size_t ws_size,
                              hipStream_t stream) {
    const float* x   = (const float*)d_in[0];
    const float* W1  = (const float*)d_in[1];
    const float* b1  = (const float*)d_in[2];
    const float* W2  = (const float*)d_in[3];
    const float* b2  = (const float*)d_in[4];
    const float* Gw1 = (const float*)d_in[5];
    const float* Gb1 = (const float*)d_in[6];
    const float* Gw2 = (const float*)d_in[7];
    const float* Gb2 = (const float*)d_in[8];
    float* out = (float*)d_out;
    float* ws  = (float*)d_ws;   // 64*96*4 + 32 = ~24.6 KB

    pack_kernel<<<1, 64, 0, stream>>>(W1, b1, W2, b2, Gw2, Gb2, ws);

    const int threads = 256;
    const int blocks = (524288 / 2) / threads;  // 1024
    moe_kernel<<<blocks, threads, 0, stream>>>(x, ws, Gw1, Gb1, out);
}

// Round 10
// 69.711 us; speedup vs baseline: 1.1933x; 1.1933x over previous
//
#include <hip/hip_runtime.h>

// Mixture-of-64-tiny-experts, fp32.
// R9: pack axis change. v2f halves = (subnet s, subnet s+32) for ONE sample
// per thread (was: 2 samples). Threads double -> 524288 -> 8 waves/SIMD from
// the grid. Rationale: revised counter model (VALUBusy is a per-CU union of
// 4 SIMDs) shows per-SIMD utilization was only ~26% — latency-bound, not
// issue-bound. More resident waves is the direct fix. Per-wave inst count
// unchanged; gating net computed once per thread (scalar), halves reduced
// only at the end.

#define NSUB 64
#define L2E  1.4426950408889634f   // log2(e)
#define L2E2 2.8853900817779268f   // 2*log2(e)

typedef float v2f __attribute__((ext_vector_type(2)));

__device__ __forceinline__ v2f pk_fma(v2f a, v2f b, v2f c) {
    return __builtin_elementwise_fma(a, b, c);
}
__device__ __forceinline__ v2f sp(float s) { return v2f{s, s}; }

// packed tanhshrink(a) = (a-1) + 2*rcp(exp2(2L*a)+1)   (R4-proven codegen)
__device__ __forceinline__ v2f tanhshrink_v(v2f a) {
    v2f s = a * L2E2;
    v2f e;
    e.x = __builtin_amdgcn_exp2f(s.x);
    e.y = __builtin_amdgcn_exp2f(s.y);
    v2f ep = e + 1.0f;
    v2f r;
    r.x = __builtin_amdgcn_rcpf(ep.x);
    r.y = __builtin_amdgcn_rcpf(ep.y);
    return pk_fma(sp(2.0f), r, a - 1.0f);
}

// packed tanh from pre-scaled input s = 2*log2e*raw
__device__ __forceinline__ v2f tanh_scaled_v(v2f s) {
    v2f e;
    e.x = __builtin_amdgcn_exp2f(s.x);
    e.y = __builtin_amdgcn_exp2f(s.y);
    v2f ep = e + 1.0f;
    v2f r;
    r.x = __builtin_amdgcn_rcpf(ep.x);
    r.y = __builtin_amdgcn_rcpf(ep.y);
    return pk_fma(sp(-2.0f), r, sp(1.0f));
}

// scalar tanhshrink for the once-per-thread gating net
__device__ __forceinline__ float tanhshrink_s(float a) {
    float e = __builtin_amdgcn_exp2f(a * L2E2);
    float r = __builtin_amdgcn_rcpf(e + 1.0f);
    return fmaf(2.0f, r, a - 1.0f);
}

// Pack per subnet-PAIR p (p, p+32), 96 floats = 48 v2f slots:
// [0:24) W1 pairs (j*6+i) | [24:28) b1 | [28:36) W2*2L (o*4+j) | [36:38) b2*2L
// [38:44) Gw2*L | [44] Gb2*L | [45:48) pad
__global__ void pack_kernel(const float* __restrict__ W1, const float* __restrict__ b1,
                            const float* __restrict__ W2, const float* __restrict__ b2,
                            const float* __restrict__ Gw2, const float* __restrict__ Gb2,
                            float* __restrict__ ws)
{
    int p = threadIdx.x;
    if (p >= 32) return;
    int sa = p, sb = p + 32;
    float* f = ws + p * 96;
    for (int i = 0; i < 24; ++i) { f[2*i]   = W1[sa*24+i];        f[2*i+1]   = W1[sb*24+i]; }
    for (int i = 0; i < 4;  ++i) { f[48+2*i] = b1[sa*4+i];        f[48+2*i+1] = b1[sb*4+i]; }
    for (int i = 0; i < 8;  ++i) { f[56+2*i] = W2[sa*8+i]*L2E2;   f[56+2*i+1] = W2[sb*8+i]*L2E2; }
    for (int i = 0; i < 2;  ++i) { f[72+2*i] = b2[sa*2+i]*L2E2;   f[72+2*i+1] = b2[sb*2+i]*L2E2; }
    for (int i = 0; i < 6;  ++i) { f[76+2*i] = Gw2[sa*6+i]*L2E;   f[76+2*i+1] = Gw2[sb*6+i]*L2E; }
    f[88] = Gb2[sa]*L2E; f[89] = Gb2[sb]*L2E;
    f[90] = 0.f; f[91] = 0.f; f[92] = 0.f; f[93] = 0.f; f[94] = 0.f; f[95] = 0.f;
}

__global__ __launch_bounds__(256) void moe_kernel(
    const float* __restrict__ x,
    const float* __restrict__ wpack,
    const float* __restrict__ Gw1, const float* __restrict__ Gb1,
    float* __restrict__ out)
{
    long t = blockIdx.x * blockDim.x + threadIdx.x;

    // one sample: 6 floats, 24B stride -> three float2 loads (8B aligned)
    const float2* xv = (const float2*)(x + t * 6);
    float2 p0 = xv[0];
    float2 p1 = xv[1];
    float2 p2 = xv[2];
    float xs[6] = {p0.x, p0.y, p1.x, p1.y, p2.x, p2.y};

    // ---- gating hidden (scalar, once per thread) ----
    float ga[6];
#pragma unroll
    for (int j = 0; j < 6; ++j) {
        float s = Gb1[j];
#pragma unroll
        for (int i = 0; i < 6; ++i)
            s = fmaf(Gw1[j * 6 + i], xs[i], s);
        ga[j] = tanhshrink_s(s);
    }

    // broadcast sample values / gating hidden into both pk halves
    v2f xa[6], gab[6];
#pragma unroll
    for (int i = 0; i < 6; ++i) xa[i] = sp(xs[i]);
#pragma unroll
    for (int j = 0; j < 6; ++j) gab[j] = sp(ga[j]);

    // ---- 32 iterations; halves cover subnets p and p+32 ----
    v2f acc0 = sp(0.f), acc1 = sp(0.f), accE = sp(0.f);

#pragma unroll 2
    for (int p = 0; p < 32; ++p) {
        const v2f* f2 = (const v2f*)(wpack + p * 96);   // 48 subnet-pair slots

        v2f h[4];
#pragma unroll
        for (int j = 0; j < 4; ++j) {
            v2f s = pk_fma(f2[j * 6 + 0], xa[0], f2[24 + j]);
#pragma unroll
            for (int i = 1; i < 6; ++i)
                s = pk_fma(f2[j * 6 + i], xa[i], s);
            h[j] = tanhshrink_v(s);
        }

        v2f o0 = pk_fma(f2[28], h[0], f2[36]);   // W2,b2 pre-scaled by 2*log2e
        o0 = pk_fma(f2[29], h[1], o0);
        o0 = pk_fma(f2[30], h[2], o0);
        o0 = pk_fma(f2[31], h[3], o0);
        o0 = tanh_scaled_v(o0);

        v2f o1 = pk_fma(f2[32], h[0], f2[37]);
        o1 = pk_fma(f2[33], h[1], o1);
        o1 = pk_fma(f2[34], h[2], o1);
        o1 = pk_fma(f2[35], h[3], o1);
        o1 = tanh_scaled_v(o1);

        v2f la = pk_fma(f2[38], gab[0], f2[44]); // Gw2,Gb2 pre-scaled by log2e
        la = pk_fma(f2[39], gab[1], la);
        la = pk_fma(f2[40], gab[2], la);
        la = pk_fma(f2[41], gab[3], la);
        la = pk_fma(f2[42], gab[4], la);
        la = pk_fma(f2[43], gab[5], la);
        v2f ea;
        ea.x = __builtin_amdgcn_exp2f(la.x);
        ea.y = __builtin_amdgcn_exp2f(la.y);

        accE = accE + ea;
        acc0 = pk_fma(ea, o0, acc0);
        acc1 = pk_fma(ea, o1, acc1);
    }

    // cross-half reduction (subnets 0-31 in .x, 32-63 in .y)
    float E  = accE.x + accE.y;
    float r  = __builtin_amdgcn_rcpf(E);
    float u0 = (acc0.x + acc0.y) * r;
    float u1 = (acc1.x + acc1.y) * r;
    float2 res; res.x = u0; res.y = u1;
    ((float2*)&out[t * 2])[0] = res;
}

extern "C" void kernel_launch(void* const* d_in, const int* in_sizes, int n_in,
                              void* d_out, int out_size, void* d_ws, size_t ws_size,
                              hipStream_t stream) {
    const float* x   = (const float*)d_in[0];
    const float* W1  = (const float*)d_in[1];
    const float* b1  = (const float*)d_in[2];
    const float* W2  = (const float*)d_in[3];
    const float* b2  = (const float*)d_in[4];
    const float* Gw1 = (const float*)d_in[5];
    const float* Gb1 = (const float*)d_in[6];
    const float* Gw2 = (const float*)d_in[7];
    const float* Gb2 = (const float*)d_in[8];
    float* out = (float*)d_out;
    float* ws  = (float*)d_ws;   // 32*96*4 = 12 KB

    pack_kernel<<<1, 64, 0, stream>>>(W1, b1, W2, b2, Gw2, Gb2, ws);

    // 1 sample/thread -> 524288 threads -> 2048 blocks (8 blocks/CU, 8 waves/SIMD)
    const int threads = 256;
    const int blocks = 524288 / threads;  // 2048
    moe_kernel<<<blocks, threads, 0, stream>>>(x, ws, Gw1, Gb1, out);
}